// Round 2
// baseline (245.394 us; speedup 1.0000x reference)
//
#include <hip/hip_runtime.h>
#include <cstddef>

#define BSZ   2
#define NN    384
#define DATOM 512
#define DPAIR 128
#define DHID  32

// ---------------------------------------------------------------------------
// Workspace layout (floats):
//   abuf [BSZ][NN][32]        offset 0       (24576)   'a' half of ab
//   bbT  [BSZ][32][NN]        offset 24576   (24576)   'b' half, transposed
//   T    [BSZ][NN][128][32]   offset 49152   (3145728) T[b,i,p,y]
// ---------------------------------------------------------------------------

#define COMP4(v,i) ((i)==0?(v).x:(i)==1?(v).y:(i)==2?(v).z:(v).w)

// Kernel A: ab = (m @ W_in^T + b_in) * op_mask; split into abuf / bbT.
// grid 96 x 256. Quad-split: h = t>>2 (64 outputs), q = t&3 splits d 4-ways.
// W_in slice (32 float4) hoisted to VGPRs once; m loads are wave-broadcast
// (all 64 lanes in one 64B line). 4-lane shfl_xor reduction at the end.
__global__ __launch_bounds__(256) void k_ab(
    const float* __restrict__ m, const float* __restrict__ op_mask,
    const float* __restrict__ W_in, const float* __restrict__ b_in,
    float* __restrict__ abuf, float* __restrict__ bbT)
{
    const int t  = threadIdx.x;
    const int h  = t >> 2;          // 0..63
    const int q  = t & 3;           // quad lane: d-offset q*4, stride 16
    const int r0 = blockIdx.x * 8;

    float4 w4[32];
    const float* wrow = W_in + (size_t)h * DATOM + q * 4;
#pragma unroll
    for (int k = 0; k < 32; ++k)
        w4[k] = *(const float4*)(wrow + k * 16);

    const float bi = b_in[h];

#pragma unroll 2
    for (int r = 0; r < 8; ++r) {
        const int row = r0 + r;
        const float* mrow = m + (size_t)row * DATOM + q * 4;
        float acc = 0.f;
#pragma unroll
        for (int k = 0; k < 32; ++k) {
            const float4 mm = *(const float4*)(mrow + k * 16);
            acc += w4[k].x * mm.x + w4[k].y * mm.y
                 + w4[k].z * mm.z + w4[k].w * mm.w;
        }
        acc += __shfl_xor(acc, 1);
        acc += __shfl_xor(acc, 2);
        if (q == 0) {
            const float val = (acc + bi) * op_mask[row];
            const int b = row / NN;
            const int n = row - b * NN;
            if (h < DHID)
                abuf[(size_t)row * DHID + h] = val;
            else
                bbT[((size_t)b * DHID + (h - DHID)) * NN + n] = val;
        }
    }
}

// Kernel B: T[b,i,p,y] = sum_x a[b,i,x] * W_out[p, x*32+y]
// grid 384 x 256: block = (i-group of 8 rows) x (p-quarter of 32).
__global__ __launch_bounds__(256) void k_T(
    const float* __restrict__ abuf, const float* __restrict__ W_out,
    float* __restrict__ T)
{
    __shared__ __align__(16) float alds[8 * DHID];
    const int t       = threadIdx.x;
    const int ig      = blockIdx.x >> 2;   // 0..95
    const int quarter = blockIdx.x & 3;    // p offset quarter*32
    const int r0      = ig * 8;            // flat (b*NN+i) base

    alds[t] = abuf[(size_t)r0 * DHID + t];
    __syncthreads();

    const int y  = t & 31;
    const int pg = t >> 5;                 // 0..7

    float acc[4][8];
#pragma unroll
    for (int c = 0; c < 4; ++c)
#pragma unroll
        for (int i = 0; i < 8; ++i) acc[c][i] = 0.f;

#pragma unroll
    for (int xc = 0; xc < 8; ++xc) {
        float4 a4[8];
#pragma unroll
        for (int i = 0; i < 8; ++i)
            a4[i] = *(const float4*)&alds[i * DHID + xc * 4];
#pragma unroll
        for (int xi = 0; xi < 4; ++xi) {
            const int x = xc * 4 + xi;
            float w[4];
#pragma unroll
            for (int c = 0; c < 4; ++c) {
                const int p = quarter * 32 + pg + 8 * c;
                w[c] = W_out[(size_t)p * (DHID * DHID) + x * DHID + y];
            }
#pragma unroll
            for (int i = 0; i < 8; ++i) {
                const float av = COMP4(a4[i], xi);
#pragma unroll
                for (int c = 0; c < 4; ++c) acc[c][i] += av * w[c];
            }
        }
    }
#pragma unroll
    for (int c = 0; c < 4; ++c) {
        const int p = quarter * 32 + pg + 8 * c;
#pragma unroll
        for (int i = 0; i < 8; ++i)
            T[(((size_t)(r0 + i)) * DPAIR + p) * DHID + y] = acc[c][i];
    }
}

// Kernel C: z[b,i,j,p] = (sum_y bb[b,j,y]*T[b,i,p,y] + b_out[p]) * op_norm
// grid 768 x 256: block = one (b,i); GEMM M=384(j) N=128(p) K=32(y).
// Tl: [y][p] chunked — p-chunk (8 floats) at stride 12 => 2-way banks (free).
#define TL_STRIDE 196   // 16 chunks * 12 + pad
#define BL_STRIDE 132

__global__ __launch_bounds__(256, 3) void k_main(
    const float* __restrict__ T, const float* __restrict__ bbT,
    const float* __restrict__ b_out, const float* __restrict__ op_norm,
    float* __restrict__ out)
{
    __shared__ __align__(16) float Tl[32 * TL_STRIDE];
    __shared__ __align__(16) float Bl[32 * BL_STRIDE];
    const int t   = threadIdx.x;
    const int blk = blockIdx.x;          // b*NN + i
    const int b   = blk / NN;

    // stage T_i: global [p][y] (coalesced) -> Tl[y][chunk(p)]
    const float4* Tg4 = (const float4*)(T + (size_t)blk * (DPAIR * DHID));
#pragma unroll
    for (int qq = 0; qq < 4; ++qq) {
        const int f4 = t + qq * 256;     // 0..1023
        const int p  = f4 >> 3;
        const int y4 = (f4 & 7) * 4;
        const float4 v = Tg4[f4];
        const int col = (p >> 3) * 12 + (p & 7);
        Tl[(y4 + 0) * TL_STRIDE + col] = v.x;
        Tl[(y4 + 1) * TL_STRIDE + col] = v.y;
        Tl[(y4 + 2) * TL_STRIDE + col] = v.z;
        Tl[(y4 + 3) * TL_STRIDE + col] = v.w;
    }

    const float onorm = op_norm[0];
    const int tp = t & 15;               // p-group: p0 = tp*8
    const int tj = t >> 4;               // j-group: j0 = tj*8
    float bo[8];
#pragma unroll
    for (int qq = 0; qq < 8; ++qq) bo[qq] = b_out[tp * 8 + qq];

    const float* Bgb = bbT + (size_t)b * DHID * NN;

    for (int jt = 0; jt < 3; ++jt) {
        __syncthreads();                 // Tl/Bl write->read & reuse fence
#pragma unroll
        for (int qq = 0; qq < 4; ++qq) {
            const int f4 = t + qq * 256; // 0..1023 over [32][32 float4]
            const int y  = f4 >> 5;
            const int j4 = (f4 & 31) * 4;
            const float4 v = *(const float4*)(Bgb + (size_t)y * NN + jt * 128 + j4);
            *(float4*)&Bl[y * BL_STRIDE + j4] = v;
        }
        __syncthreads();

        float acc[8][8];
#pragma unroll
        for (int jj = 0; jj < 8; ++jj)
#pragma unroll
            for (int pp = 0; pp < 8; ++pp) acc[jj][pp] = 0.f;

#pragma unroll 4
        for (int y = 0; y < 32; ++y) {
            const float* trow = &Tl[y * TL_STRIDE + tp * 12];
            const float4 t0 = *(const float4*)(trow);
            const float4 t1 = *(const float4*)(trow + 4);
            const float* brow = &Bl[y * BL_STRIDE + tj * 8];
            const float4 b0 = *(const float4*)(brow);
            const float4 b1 = *(const float4*)(brow + 4);
#pragma unroll
            for (int jj = 0; jj < 8; ++jj) {
                const float bj = (jj < 4) ? COMP4(b0, jj) : COMP4(b1, jj - 4);
#pragma unroll
                for (int pp = 0; pp < 8; ++pp) {
                    const float tv = (pp < 4) ? COMP4(t0, pp) : COMP4(t1, pp - 4);
                    acc[jj][pp] += bj * tv;
                }
            }
        }

        float* orow = out + (((size_t)blk * NN) + jt * 128 + tj * 8) * DPAIR + tp * 8;
#pragma unroll
        for (int jj = 0; jj < 8; ++jj) {
            float4 o0, o1;
            o0.x = (acc[jj][0] + bo[0]) * onorm;
            o0.y = (acc[jj][1] + bo[1]) * onorm;
            o0.z = (acc[jj][2] + bo[2]) * onorm;
            o0.w = (acc[jj][3] + bo[3]) * onorm;
            o1.x = (acc[jj][4] + bo[4]) * onorm;
            o1.y = (acc[jj][5] + bo[5]) * onorm;
            o1.z = (acc[jj][6] + bo[6]) * onorm;
            o1.w = (acc[jj][7] + bo[7]) * onorm;
            *(float4*)(orow + (size_t)jj * DPAIR)     = o0;
            *(float4*)(orow + (size_t)jj * DPAIR + 4) = o1;
        }
    }
}

extern "C" void kernel_launch(void* const* d_in, const int* in_sizes, int n_in,
                              void* d_out, int out_size, void* d_ws, size_t ws_size,
                              hipStream_t stream)
{
    const float* m       = (const float*)d_in[0];
    const float* op_mask = (const float*)d_in[1];
    const float* op_norm = (const float*)d_in[2];
    const float* W_in    = (const float*)d_in[3];
    const float* b_in    = (const float*)d_in[4];
    const float* W_out   = (const float*)d_in[5];
    const float* b_out   = (const float*)d_in[6];
    float* out = (float*)d_out;

    float* ws   = (float*)d_ws;
    float* abuf = ws;                  // 24576 floats
    float* bbT  = ws + 24576;          // 24576 floats
    float* T    = ws + 49152;          // 3145728 floats

    hipLaunchKernelGGL(k_ab,   dim3(BSZ * NN / 8), dim3(256), 0, stream,
                       m, op_mask, W_in, b_in, abuf, bbT);
    hipLaunchKernelGGL(k_T,    dim3((BSZ * NN / 8) * 4), dim3(256), 0, stream,
                       abuf, W_out, T);
    hipLaunchKernelGGL(k_main, dim3(BSZ * NN),     dim3(256), 0, stream,
                       T, bbT, b_out, op_norm, out);
}

// Round 3
// 206.224 us; speedup vs baseline: 1.1899x; 1.1899x over previous
//
#include <hip/hip_runtime.h>
#include <cstddef>

#define BSZ   2
#define NN    384
#define DATOM 512
#define DPAIR 128
#define DHID  32

// ---------------------------------------------------------------------------
// Workspace layout (floats):
//   abuf [BSZ][NN][32]        offset 0       (24576)   'a' half of ab
//   bbT  [BSZ][32][NN]        offset 24576   (24576)   'b' half, transposed
//   T    [BSZ][NN][128][32]   offset 49152   (3145728) T[b,i,p,y]
// ---------------------------------------------------------------------------

#define COMP4(v,i) ((i)==0?(v).x:(i)==1?(v).y:(i)==2?(v).z:(v).w)

// Kernel A (round-1 form): ab = (m @ W_in^T + b_in) * op_mask; split.
// grid 192 x 256: block handles 4 rows (b*NN+n).
__global__ __launch_bounds__(256) void k_ab(
    const float* __restrict__ m, const float* __restrict__ op_mask,
    const float* __restrict__ W_in, const float* __restrict__ b_in,
    float* __restrict__ abuf, float* __restrict__ bbT)
{
    __shared__ __align__(16) float mrow[4 * DATOM];
    const int t  = threadIdx.x;
    const int r0 = blockIdx.x * 4;

    const float4* msrc = (const float4*)(m + (size_t)r0 * DATOM);
    float4* mdst = (float4*)mrow;
    mdst[t]       = msrc[t];
    mdst[t + 256] = msrc[t + 256];
    __syncthreads();

    const int h    = t & 63;
    const int rloc = t >> 6;
    const int row  = r0 + rloc;

    const float4* wrow = (const float4*)(W_in + (size_t)h * DATOM);
    const float4* ml   = (const float4*)(mrow + rloc * DATOM);
    float acc = 0.f;
#pragma unroll 16
    for (int d4 = 0; d4 < DATOM / 4; ++d4) {
        const float4 w  = wrow[d4];
        const float4 mm = ml[d4];
        acc += w.x * mm.x + w.y * mm.y + w.z * mm.z + w.w * mm.w;
    }
    const float val = (acc + b_in[h]) * op_mask[row];
    const int b = row / NN;
    const int n = row - b * NN;
    if (h < DHID)
        abuf[(size_t)row * DHID + h] = val;
    else
        bbT[((size_t)b * DHID + (h - DHID)) * NN + n] = val;
}

// Kernel B (round-2 form): T[b,i,p,y] = sum_x a[b,i,x] * W_out[p, x*32+y]
// grid 384 x 256: block = (i-group of 8 rows) x (p-quarter of 32).
__global__ __launch_bounds__(256) void k_T(
    const float* __restrict__ abuf, const float* __restrict__ W_out,
    float* __restrict__ T)
{
    __shared__ __align__(16) float alds[8 * DHID];
    const int t       = threadIdx.x;
    const int ig      = blockIdx.x >> 2;   // 0..95
    const int quarter = blockIdx.x & 3;    // p offset quarter*32
    const int r0      = ig * 8;            // flat (b*NN+i) base

    alds[t] = abuf[(size_t)r0 * DHID + t];
    __syncthreads();

    const int y  = t & 31;
    const int pg = t >> 5;                 // 0..7

    float acc[4][8];
#pragma unroll
    for (int c = 0; c < 4; ++c)
#pragma unroll
        for (int i = 0; i < 8; ++i) acc[c][i] = 0.f;

#pragma unroll
    for (int xc = 0; xc < 8; ++xc) {
        float4 a4[8];
#pragma unroll
        for (int i = 0; i < 8; ++i)
            a4[i] = *(const float4*)&alds[i * DHID + xc * 4];
#pragma unroll
        for (int xi = 0; xi < 4; ++xi) {
            const int x = xc * 4 + xi;
            float w[4];
#pragma unroll
            for (int c = 0; c < 4; ++c) {
                const int p = quarter * 32 + pg + 8 * c;
                w[c] = W_out[(size_t)p * (DHID * DHID) + x * DHID + y];
            }
#pragma unroll
            for (int i = 0; i < 8; ++i) {
                const float av = COMP4(a4[i], xi);
#pragma unroll
                for (int c = 0; c < 4; ++c) acc[c][i] += av * w[c];
            }
        }
    }
#pragma unroll
    for (int c = 0; c < 4; ++c) {
        const int p = quarter * 32 + pg + 8 * c;
#pragma unroll
        for (int i = 0; i < 8; ++i)
            T[(((size_t)(r0 + i)) * DPAIR + p) * DHID + y] = acc[c][i];
    }
}

// Kernel C: z[b,i,j,p] = (sum_y bb[b,j,y]*T[b,i,p,y] + b_out[p]) * op_norm
// grid 768 x 256: block = one (b,i); GEMM M=384(j) N=128(p) K=32(y).
// NEW: Bl holds ALL 384 j (staged once) -> ONE __syncthreads per block.
// Register tile 12j x 8p, j swept in 2 passes of 192.
// Tl: [y][p] chunked, p-chunk (8 floats) at stride 12 => 2-way banks (free).
// Bl reads: tj*12 mod 32 -> disjoint 4-bank groups across tj => conflict-free.
#define TL_STRIDE 196   // 16 chunks * 12 + pad
#define BL2       388   // 384 + 4; row start bank offset 4, b128-aligned

__global__ __launch_bounds__(256, 2) void k_main(
    const float* __restrict__ T, const float* __restrict__ bbT,
    const float* __restrict__ b_out, const float* __restrict__ op_norm,
    float* __restrict__ out)
{
    __shared__ __align__(16) float Tl[32 * TL_STRIDE];  // 24.5 KB
    __shared__ __align__(16) float Bl[32 * BL2];        // 48.5 KB
    const int t   = threadIdx.x;
    const int blk = blockIdx.x;          // b*NN + i
    const int b   = blk / NN;

    // stage T_i: global [p][y] (coalesced) -> Tl[y][chunk(p)]
    const float4* Tg4 = (const float4*)(T + (size_t)blk * (DPAIR * DHID));
#pragma unroll
    for (int q = 0; q < 4; ++q) {
        const int f4 = t + q * 256;      // 0..1023
        const int p  = f4 >> 3;
        const int y4 = (f4 & 7) * 4;
        const float4 v = Tg4[f4];
        const int col = (p >> 3) * 12 + (p & 7);
        Tl[(y4 + 0) * TL_STRIDE + col] = v.x;
        Tl[(y4 + 1) * TL_STRIDE + col] = v.y;
        Tl[(y4 + 2) * TL_STRIDE + col] = v.z;
        Tl[(y4 + 3) * TL_STRIDE + col] = v.w;
    }

    // stage ALL of B_b: bbT[b][y][0..383] -> Bl[y][j]  (3072 float4)
    const float* Bgb = bbT + (size_t)b * DHID * NN;
#pragma unroll
    for (int q = 0; q < 12; ++q) {
        const int f4 = t + q * 256;      // 0..3071
        const int y  = f4 / 96;
        const int j4 = (f4 - y * 96) * 4;
        const float4 v = *(const float4*)(Bgb + (size_t)y * NN + j4);
        *(float4*)&Bl[y * BL2 + j4] = v;
    }

    const float onorm = op_norm[0];
    const int tp = t & 15;               // p-group: p0 = tp*8
    const int tj = t >> 4;               // j-group of 12 (16 groups x 2 passes)
    float bo[8];
#pragma unroll
    for (int q = 0; q < 8; ++q) bo[q] = b_out[tp * 8 + q];

    __syncthreads();                     // the ONLY barrier

#pragma unroll
    for (int pass = 0; pass < 2; ++pass) {
        float acc[12][8];
#pragma unroll
        for (int jj = 0; jj < 12; ++jj)
#pragma unroll
            for (int pp = 0; pp < 8; ++pp) acc[jj][pp] = 0.f;

        const int jbase = pass * 192 + tj * 12;

#pragma unroll 4
        for (int y = 0; y < 32; ++y) {
            const float* trow = &Tl[y * TL_STRIDE + tp * 12];
            const float4 t0 = *(const float4*)(trow);
            const float4 t1 = *(const float4*)(trow + 4);
            const float* brow = &Bl[y * BL2 + jbase];
            const float4 b0 = *(const float4*)(brow);
            const float4 b1 = *(const float4*)(brow + 4);
            const float4 b2 = *(const float4*)(brow + 8);
#pragma unroll
            for (int jj = 0; jj < 12; ++jj) {
                const float bj = (jj < 4) ? COMP4(b0, jj)
                               : (jj < 8) ? COMP4(b1, jj - 4)
                                          : COMP4(b2, jj - 8);
#pragma unroll
                for (int pp = 0; pp < 8; ++pp) {
                    const float tv = (pp < 4) ? COMP4(t0, pp) : COMP4(t1, pp - 4);
                    acc[jj][pp] += bj * tv;
                }
            }
        }

        float* orow = out + (((size_t)blk * NN) + jbase) * DPAIR + tp * 8;
#pragma unroll
        for (int jj = 0; jj < 12; ++jj) {
            float4 o0, o1;
            o0.x = (acc[jj][0] + bo[0]) * onorm;
            o0.y = (acc[jj][1] + bo[1]) * onorm;
            o0.z = (acc[jj][2] + bo[2]) * onorm;
            o0.w = (acc[jj][3] + bo[3]) * onorm;
            o1.x = (acc[jj][4] + bo[4]) * onorm;
            o1.y = (acc[jj][5] + bo[5]) * onorm;
            o1.z = (acc[jj][6] + bo[6]) * onorm;
            o1.w = (acc[jj][7] + bo[7]) * onorm;
            *(float4*)(orow + (size_t)jj * DPAIR)     = o0;
            *(float4*)(orow + (size_t)jj * DPAIR + 4) = o1;
        }
    }
}

extern "C" void kernel_launch(void* const* d_in, const int* in_sizes, int n_in,
                              void* d_out, int out_size, void* d_ws, size_t ws_size,
                              hipStream_t stream)
{
    const float* m       = (const float*)d_in[0];
    const float* op_mask = (const float*)d_in[1];
    const float* op_norm = (const float*)d_in[2];
    const float* W_in    = (const float*)d_in[3];
    const float* b_in    = (const float*)d_in[4];
    const float* W_out   = (const float*)d_in[5];
    const float* b_out   = (const float*)d_in[6];
    float* out = (float*)d_out;

    float* ws   = (float*)d_ws;
    float* abuf = ws;                  // 24576 floats
    float* bbT  = ws + 24576;          // 24576 floats
    float* T    = ws + 49152;          // 3145728 floats

    hipLaunchKernelGGL(k_ab,   dim3(BSZ * NN / 4),       dim3(256), 0, stream,
                       m, op_mask, W_in, b_in, abuf, bbT);
    hipLaunchKernelGGL(k_T,    dim3((BSZ * NN / 8) * 4), dim3(256), 0, stream,
                       abuf, W_out, T);
    hipLaunchKernelGGL(k_main, dim3(BSZ * NN),           dim3(256), 0, stream,
                       T, bbT, b_out, op_norm, out);
}

// Round 4
// 192.468 us; speedup vs baseline: 1.2750x; 1.0715x over previous
//
#include <hip/hip_runtime.h>
#include <cstddef>

#define BSZ   2
#define NN    384
#define DATOM 512
#define DPAIR 128
#define DHID  32

// ---------------------------------------------------------------------------
// Workspace layout (floats):
//   abuf [BSZ][NN][32]        offset 0       (24576)   'a' half of ab
//   bbT  [BSZ][32][NN]        offset 24576   (24576)   'b' half, transposed
//   T    [BSZ][NN][128][32]   offset 49152   (3145728) T[b,i,p,y]
// ---------------------------------------------------------------------------

#define COMP4(v,i) ((i)==0?(v).x:(i)==1?(v).y:(i)==2?(v).z:(v).w)

// Kernel A (v4): ab = (m @ W_in^T + b_in) * op_mask; split into abuf / bbT.
// grid 768 x 256 (3 blocks/CU): block = ONE row. h = t>>2, q = t&3 splits d
// 4-ways (128 floats each). W_in loads touch 16 lines/wave (vs 64 before);
// m loads are wave-broadcast. Intra-quad shfl reduction, no LDS, no barrier.
__global__ __launch_bounds__(256) void k_ab(
    const float* __restrict__ m, const float* __restrict__ op_mask,
    const float* __restrict__ W_in, const float* __restrict__ b_in,
    float* __restrict__ abuf, float* __restrict__ bbT)
{
    const int t   = threadIdx.x;
    const int h   = t >> 2;          // 0..63
    const int q   = t & 3;           // d-offset q*4, stride 16 floats
    const int row = blockIdx.x;      // b*NN + n

    const float* wrow = W_in + (size_t)h * DATOM + q * 4;
    const float* mrow = m + (size_t)row * DATOM + q * 4;
    float acc = 0.f;
#pragma unroll
    for (int k = 0; k < 32; ++k) {
        const float4 w  = *(const float4*)(wrow + k * 16);
        const float4 mm = *(const float4*)(mrow + k * 16);
        acc += w.x * mm.x + w.y * mm.y + w.z * mm.z + w.w * mm.w;
    }
    acc += __shfl_xor(acc, 1);
    acc += __shfl_xor(acc, 2);
    if (q == 0) {
        const float val = (acc + b_in[h]) * op_mask[row];
        const int b = row / NN;
        const int n = row - b * NN;
        if (h < DHID)
            abuf[(size_t)row * DHID + h] = val;
        else
            bbT[((size_t)b * DHID + (h - DHID)) * NN + n] = val;
    }
}

// Kernel B (v4): T[b,i,p,y] = sum_x a[b,i,x] * W_out[p, x*32+y]
// grid 768 x 256 (3 blocks/CU): block = (i-group of 8 rows) x (p-16th: oct).
// Per thread: 64 W_out scalar loads (2x128B segments/wave), 64 LDS b128
// broadcasts, 512 FMA. acc[2][8].
__global__ __launch_bounds__(256) void k_T(
    const float* __restrict__ abuf, const float* __restrict__ W_out,
    float* __restrict__ T)
{
    __shared__ __align__(16) float alds[8 * DHID];
    const int t   = threadIdx.x;
    const int ig  = blockIdx.x >> 3;   // 0..95
    const int oct = blockIdx.x & 7;    // p base = oct*16
    const int r0  = ig * 8;            // flat (b*NN+i) base

    alds[t] = abuf[(size_t)r0 * DHID + t];
    __syncthreads();

    const int y  = t & 31;
    const int pg = t >> 5;             // 0..7

    float acc[2][8];
#pragma unroll
    for (int c = 0; c < 2; ++c)
#pragma unroll
        for (int i = 0; i < 8; ++i) acc[c][i] = 0.f;

#pragma unroll
    for (int xc = 0; xc < 8; ++xc) {
        float4 a4[8];
#pragma unroll
        for (int i = 0; i < 8; ++i)
            a4[i] = *(const float4*)&alds[i * DHID + xc * 4];  // broadcast
#pragma unroll
        for (int xi = 0; xi < 4; ++xi) {
            const int x = xc * 4 + xi;
            float w[2];
#pragma unroll
            for (int c = 0; c < 2; ++c) {
                const int p = oct * 16 + c * 8 + pg;
                w[c] = W_out[(size_t)p * (DHID * DHID) + x * DHID + y];
            }
#pragma unroll
            for (int i = 0; i < 8; ++i) {
                const float av = COMP4(a4[i], xi);
#pragma unroll
                for (int c = 0; c < 2; ++c) acc[c][i] += av * w[c];
            }
        }
    }
#pragma unroll
    for (int c = 0; c < 2; ++c) {
        const int p = oct * 16 + c * 8 + pg;
#pragma unroll
        for (int i = 0; i < 8; ++i)
            T[(((size_t)(r0 + i)) * DPAIR + p) * DHID + y] = acc[c][i];
    }
}

// Kernel C (FROZEN from round 3): z[b,i,j,p] =
//   (sum_y bb[b,j,y]*T[b,i,p,y] + b_out[p]) * op_norm
// grid 768 x 256: block = one (b,i); Bl holds ALL 384 j; ONE barrier.
// Register tile 12j x 8p, j swept in 2 passes of 192.
#define TL_STRIDE 196   // 16 chunks * 12 + pad
#define BL2       388   // 384 + 4; row start bank offset 4, b128-aligned

__global__ __launch_bounds__(256, 2) void k_main(
    const float* __restrict__ T, const float* __restrict__ bbT,
    const float* __restrict__ b_out, const float* __restrict__ op_norm,
    float* __restrict__ out)
{
    __shared__ __align__(16) float Tl[32 * TL_STRIDE];  // 24.5 KB
    __shared__ __align__(16) float Bl[32 * BL2];        // 48.5 KB
    const int t   = threadIdx.x;
    const int blk = blockIdx.x;          // b*NN + i
    const int b   = blk / NN;

    // stage T_i: global [p][y] (coalesced) -> Tl[y][chunk(p)]
    const float4* Tg4 = (const float4*)(T + (size_t)blk * (DPAIR * DHID));
#pragma unroll
    for (int q = 0; q < 4; ++q) {
        const int f4 = t + q * 256;      // 0..1023
        const int p  = f4 >> 3;
        const int y4 = (f4 & 7) * 4;
        const float4 v = Tg4[f4];
        const int col = (p >> 3) * 12 + (p & 7);
        Tl[(y4 + 0) * TL_STRIDE + col] = v.x;
        Tl[(y4 + 1) * TL_STRIDE + col] = v.y;
        Tl[(y4 + 2) * TL_STRIDE + col] = v.z;
        Tl[(y4 + 3) * TL_STRIDE + col] = v.w;
    }

    // stage ALL of B_b: bbT[b][y][0..383] -> Bl[y][j]  (3072 float4)
    const float* Bgb = bbT + (size_t)b * DHID * NN;
#pragma unroll
    for (int q = 0; q < 12; ++q) {
        const int f4 = t + q * 256;      // 0..3071
        const int y  = f4 / 96;
        const int j4 = (f4 - y * 96) * 4;
        const float4 v = *(const float4*)(Bgb + (size_t)y * NN + j4);
        *(float4*)&Bl[y * BL2 + j4] = v;
    }

    const float onorm = op_norm[0];
    const int tp = t & 15;               // p-group: p0 = tp*8
    const int tj = t >> 4;               // j-group of 12 (16 groups x 2 passes)
    float bo[8];
#pragma unroll
    for (int q = 0; q < 8; ++q) bo[q] = b_out[tp * 8 + q];

    __syncthreads();                     // the ONLY barrier

#pragma unroll
    for (int pass = 0; pass < 2; ++pass) {
        float acc[12][8];
#pragma unroll
        for (int jj = 0; jj < 12; ++jj)
#pragma unroll
            for (int pp = 0; pp < 8; ++pp) acc[jj][pp] = 0.f;

        const int jbase = pass * 192 + tj * 12;

#pragma unroll 4
        for (int y = 0; y < 32; ++y) {
            const float* trow = &Tl[y * TL_STRIDE + tp * 12];
            const float4 t0 = *(const float4*)(trow);
            const float4 t1 = *(const float4*)(trow + 4);
            const float* brow = &Bl[y * BL2 + jbase];
            const float4 b0 = *(const float4*)(brow);
            const float4 b1 = *(const float4*)(brow + 4);
            const float4 b2 = *(const float4*)(brow + 8);
#pragma unroll
            for (int jj = 0; jj < 12; ++jj) {
                const float bj = (jj < 4) ? COMP4(b0, jj)
                               : (jj < 8) ? COMP4(b1, jj - 4)
                                          : COMP4(b2, jj - 8);
#pragma unroll
                for (int pp = 0; pp < 8; ++pp) {
                    const float tv = (pp < 4) ? COMP4(t0, pp) : COMP4(t1, pp - 4);
                    acc[jj][pp] += bj * tv;
                }
            }
        }

        float* orow = out + (((size_t)blk * NN) + jbase) * DPAIR + tp * 8;
#pragma unroll
        for (int jj = 0; jj < 12; ++jj) {
            float4 o0, o1;
            o0.x = (acc[jj][0] + bo[0]) * onorm;
            o0.y = (acc[jj][1] + bo[1]) * onorm;
            o0.z = (acc[jj][2] + bo[2]) * onorm;
            o0.w = (acc[jj][3] + bo[3]) * onorm;
            o1.x = (acc[jj][4] + bo[4]) * onorm;
            o1.y = (acc[jj][5] + bo[5]) * onorm;
            o1.z = (acc[jj][6] + bo[6]) * onorm;
            o1.w = (acc[jj][7] + bo[7]) * onorm;
            *(float4*)(orow + (size_t)jj * DPAIR)     = o0;
            *(float4*)(orow + (size_t)jj * DPAIR + 4) = o1;
        }
    }
}

extern "C" void kernel_launch(void* const* d_in, const int* in_sizes, int n_in,
                              void* d_out, int out_size, void* d_ws, size_t ws_size,
                              hipStream_t stream)
{
    const float* m       = (const float*)d_in[0];
    const float* op_mask = (const float*)d_in[1];
    const float* op_norm = (const float*)d_in[2];
    const float* W_in    = (const float*)d_in[3];
    const float* b_in    = (const float*)d_in[4];
    const float* W_out   = (const float*)d_in[5];
    const float* b_out   = (const float*)d_in[6];
    float* out = (float*)d_out;

    float* ws   = (float*)d_ws;
    float* abuf = ws;                  // 24576 floats
    float* bbT  = ws + 24576;          // 24576 floats
    float* T    = ws + 49152;          // 3145728 floats

    hipLaunchKernelGGL(k_ab,   dim3(BSZ * NN),           dim3(256), 0, stream,
                       m, op_mask, W_in, b_in, abuf, bbT);
    hipLaunchKernelGGL(k_T,    dim3((BSZ * NN / 8) * 8), dim3(256), 0, stream,
                       abuf, W_out, T);
    hipLaunchKernelGGL(k_main, dim3(BSZ * NN),           dim3(256), 0, stream,
                       T, bbT, b_out, op_norm, out);
}